// Round 7
// baseline (189.047 us; speedup 1.0000x reference)
//
#include <hip/hip_runtime.h>
#include <stdint.h>

#define H 192
#define W 192
#define CIN 32
#define NOUT 32
#define NB 16
#define PADI 4

#define HT 16          // output rows per block
#define WT2 32         // output cols per block
#define RR2 24         // HT + 8 halo
#define RC2 40         // WT2 + 8 halo
#define NT (NB * (H / HT) * (W / WT2))   // 16*12*6 = 1152

typedef __attribute__((ext_vector_type(8))) short bf16x8;
typedef __attribute__((ext_vector_type(4))) float f32x4;

__device__ __forceinline__ unsigned short f2bf(float f) {
    union { float f; unsigned int u; } v; v.f = f;
    unsigned int r = v.u + 0x7fffu + ((v.u >> 16) & 1u);
    return (unsigned short)(r >> 16);
}

// HW round-to-nearest-even pack of 2 f32 -> 2 bf16 in one VALU op.
__device__ __forceinline__ unsigned int cvtpk_bf16(float lo, float hi) {
    unsigned int r;
    asm("v_cvt_pk_bf16_f32 %0, %1, %2" : "=v"(r) : "v"(lo), "v"(hi));
    return r;
}

// ---- Gaussian kernel generation (unchanged layout) ----
// W2g[mt][tap][quad][m][j]  (mt=o>>4, m=o&15, quad=i>>3, j=i&7)
__global__ void genw_kernel(const float* __restrict__ wp, unsigned short* __restrict__ W2g) {
    const int b = blockIdx.x;          // = o*32 + i
    const int o = b >> 5;
    const int i = b & 31;
    const int t = threadIdx.x;         // 0..127

    float sx = wp[b * 3 + 0], sy = wp[b * 3 + 1], th = wp[b * 3 + 2];
    float rad = th / 180.0f * 3.14159265358979323846f;
    float co = cosf(rad), si = sinf(rad);
    float sx2 = sx * sx, sy2 = sy * sy;
    float a = co * co * sx2 + si * si * sy2;
    float bb = co * si * (sx2 - sy2);
    float d = si * si * sx2 + co * co * sy2;
    float det = a * d - bb * bb;
    float ia = d / det, ib = -bb / det, idd = a / det;

    const int tap = t;
    float e = 0.0f;
    if (tap < 81) {
        float xx = (float)(tap % 9 - 4);
        float yy = (float)(tap / 9 - 4);
        float q = ia * xx * xx + 2.0f * ib * xx * yy + idd * yy * yy;
        e = expf(-0.5f * q);
    }
    float s = e;
    #pragma unroll
    for (int off = 32; off > 0; off >>= 1) s += __shfl_down(s, off);
    __shared__ float ws[2];
    if ((t & 63) == 0) ws[t >> 6] = s;
    __syncthreads();
    float total = ws[0] + ws[1];

    if (tap < 81) {
        int mt = o >> 4, m = o & 15, quad = i >> 3, j = i & 7;
        W2g[((((mt * 81 + tap) * 4 + quad) * 16 + m) << 3) + j] = f2bf(e / total);
    }
}

// ---- Conv kernel: mt-merged implicit GEMM ----
// KEY INSIGHT (R6 PMC arithmetic): the old 16x16 structure was LDS-READ-BW
// bound (18,432 cyc/CU/gen LDS vs 12,570 MFMA -> 69us floor; R1 measured
// 71.6). Fix: each wave computes BOTH och-halves (mt0+mt1) from one bfrag
// read -> 9 MFMA per ds_read_b128 instead of 4.5. LDS demand drops to
// ~8.6us total; kernel becomes MFMA-bound (47us floor).
// Tile 16x32, 4 waves = 2 row-halves x 2 col-halves; per wave: 32 och x
// 8 rows x 16 cols. acc0[8]+acc1[8] (64 VGPR), A dbuf both mt (144 VGPR)
// -> __launch_bounds__(256,2): 256-VGPR budget, LDS 61,440B, 2 blocks/CU.
// dx loop is step-2 with NAMED A-buffer pairs (all register indices
// compile-time; rule-20 safe). Inner rr/dy loop identical to champion.
__global__ __launch_bounds__(256, 2) void conv_kernel(
    const float* __restrict__ x, const unsigned short* __restrict__ W2g,
    const float* __restrict__ bias, float* __restrict__ out)
{
    __shared__ __align__(16) unsigned short ldsx[4 * RR2 * RC2 * 8];  // 61,440 B

    const int t = threadIdx.x;
    // XCD-contiguous swizzle: 8 classes x 144 tiles (bijective: 1152 = 8*144)
    const int bid = (blockIdx.x & 7) * 144 + (blockIdx.x >> 3);
    const int wb = bid % (W / WT2);                 // 0..5
    const int hb = (bid / (W / WT2)) % (H / HT);    // 0..11
    const int n  = bid / ((W / WT2) * (H / HT));    // 0..15
    const int row0 = hb * HT - PADI;
    const int col0 = wb * WT2 - PADI;
    const float* xn = x + (size_t)n * CIN * H * W;

    const int wave = t >> 6;
    const int lane = t & 63;
    const int l15 = lane & 15;      // A: m-row / B: pixel col / D: col
    const int quad4 = lane >> 4;    // A/B: k-group (8 ch) / D: och-quad
    const int ch2 = wave & 1;       // col half (16 px)
    const int rbase = (wave >> 1) * 8;  // output-row base within tile

    // bias fragments for both och-halves (folded into acc init)
    float bb0[4], bb1[4];
    #pragma unroll
    for (int reg = 0; reg < 4; reg++) {
        bb0[reg] = bias[quad4 * 4 + reg];
        bb1[reg] = bias[16 + quad4 * 4 + reg];
    }

    // ---- phase 1: issue ALL staging loads (120 fp32 in VGPRs; 256-reg budget) ----
    float v[15][8];
    #pragma unroll
    for (int it = 0; it < 15; ++it) {
        int idx = it * 256 + t;
        int w = idx % RC2;
        int r = (idx / RC2) % RR2;
        int quad = idx / (RC2 * RR2);
        int row = row0 + r, col = col0 + w;
        #pragma unroll
        for (int k = 0; k < 8; k++) v[it][k] = 0.0f;
        if ((unsigned)row < (unsigned)H && (unsigned)col < (unsigned)W) {
            const float* p = xn + ((size_t)(quad * 8) * H + row) * W + col;
            #pragma unroll
            for (int k = 0; k < 8; k++) v[it][k] = p[(size_t)k * H * W];
        }
    }
    // ---- phase 2: pack (v_cvt_pk_bf16_f32) + LDS write (lane-linear b128) ----
    #pragma unroll
    for (int it = 0; it < 15; ++it) {
        int idx = it * 256 + t;
        unsigned int d[4];
        #pragma unroll
        for (int k = 0; k < 4; k++)
            d[k] = cvtpk_bf16(v[it][2 * k], v[it][2 * k + 1]);
        *(uint4*)&ldsx[(size_t)idx * 8] = make_uint4(d[0], d[1], d[2], d[3]);
    }

    const bf16x8* __restrict__ Wpt = (const bf16x8*)W2g;

    // A-frag double buffers, both mt, named (no runtime indexing)
    bf16x8 Aa0[9], Aa1[9], Ab0[9], Ab1[9];
    #pragma unroll
    for (int dy = 0; dy < 9; dy++) {
        Aa0[dy] = Wpt[((dy * 9 + 0) * 4 + quad4) * 16 + l15];
        Aa1[dy] = Wpt[((81 + dy * 9 + 0) * 4 + quad4) * 16 + l15];
    }

    __syncthreads();

    f32x4 acc0[8], acc1[8];
    #pragma unroll
    for (int i = 0; i < 8; i++) {
        acc0[i] = (f32x4){bb0[0], bb0[1], bb0[2], bb0[3]};
        acc1[i] = (f32x4){bb1[0], bb1[1], bb1[2], bb1[3]};
    }

    const unsigned short* bptr =
        &ldsx[(size_t)(((quad4 * RR2 + rbase) * RC2) + ch2 * 16 + l15) * 8];

    // one dx step: use (Ac0,Ac1), prefetch taps for dx=pf into (An0,An1)
#define DX_BODY(Ac0, Ac1, An0, An1, dxv, pfv, DO_PF)                          \
    {                                                                          \
        if (DO_PF) {                                                           \
            _Pragma("unroll")                                                  \
            for (int dy = 0; dy < 9; dy++) {                                   \
                An0[dy] = Wpt[((dy * 9 + (pfv)) * 4 + quad4) * 16 + l15];      \
                An1[dy] = Wpt[((81 + dy * 9 + (pfv)) * 4 + quad4) * 16 + l15]; \
            }                                                                  \
        }                                                                      \
        __builtin_amdgcn_s_setprio(1);                                         \
        _Pragma("unroll")                                                      \
        for (int rr = 0; rr < 16; rr++) {                                      \
            const bf16x8 bfrag =                                               \
                *(const bf16x8*)&bptr[(size_t)(rr * RC2 + (dxv)) * 8];         \
            _Pragma("unroll")                                                  \
            for (int dy = 0; dy < 9; dy++) {                                   \
                const int orr = rr - dy;                                       \
                if (orr >= 0 && orr < 8) {                                     \
                    acc0[orr] = __builtin_amdgcn_mfma_f32_16x16x32_bf16(       \
                        Ac0[dy], bfrag, acc0[orr], 0, 0, 0);                   \
                    acc1[orr] = __builtin_amdgcn_mfma_f32_16x16x32_bf16(       \
                        Ac1[dy], bfrag, acc1[orr], 0, 0, 0);                   \
                }                                                              \
            }                                                                  \
        }                                                                      \
        __builtin_amdgcn_s_setprio(0);                                         \
    }

    for (int dx = 0; dx < 8; dx += 2) {
        DX_BODY(Aa0, Aa1, Ab0, Ab1, dx, dx + 1, true);       // even: use Aa, fetch dx+1
        DX_BODY(Ab0, Ab1, Aa0, Aa1, dx + 1, dx + 2, true);   // odd: use Ab, fetch dx+2
    }
    DX_BODY(Aa0, Aa1, Ab0, Ab1, 8, 0, false);                // dx=8, no prefetch
#undef DX_BODY

    // ---- epilogue: D col = lane&15 (pixel), row = quad4*4 + reg (och) ----
    float* outn = out + (size_t)n * NOUT * H * W;
    const int col = wb * WT2 + ch2 * 16 + l15;
    #pragma unroll
    for (int orr = 0; orr < 8; orr++) {
        const int row = hb * HT + rbase + orr;
        #pragma unroll
        for (int reg = 0; reg < 4; reg++) {
            outn[((size_t)(quad4 * 4 + reg) * H + row) * W + col] = acc0[orr][reg];
            outn[((size_t)(16 + quad4 * 4 + reg) * H + row) * W + col] = acc1[orr][reg];
        }
    }
}

extern "C" void kernel_launch(void* const* d_in, const int* in_sizes, int n_in,
                              void* d_out, int out_size, void* d_ws, size_t ws_size,
                              hipStream_t stream) {
    const float* x    = (const float*)d_in[0];
    const float* wp   = (const float*)d_in[1];   // (32,32,3)
    const float* bias = (const float*)d_in[2];   // (32,)
    float* out = (float*)d_out;
    unsigned short* W2g = (unsigned short*)d_ws; // 165,888 B of scratch

    genw_kernel<<<NOUT * CIN, 128, 0, stream>>>(wp, W2g);
    conv_kernel<<<NT, 256, 0, stream>>>(x, W2g, bias, out);
}